// Round 1
// baseline (530.837 us; speedup 1.0000x reference)
//
#include <hip/hip_runtime.h>
#include <stdint.h>

#define MQTOT 1024
#define DDIM 64
#define NCAND 1048576
#define NCHUNK 2048
#define CHUNKS (NCAND / NCHUNK)   /* 512 */
#define NSUB 32
#define NSUBS (NCHUNK / NSUB)     /* 64 */
#define KTOP 100
#define CAP 1024

typedef short short8 __attribute__((ext_vector_type(8)));
typedef float f32x4 __attribute__((ext_vector_type(4)));

__device__ __forceinline__ unsigned f2bfu(float f) {
  unsigned u = __builtin_bit_cast(unsigned, f);
  return (u + 0x7FFFu + ((u >> 16) & 1u)) >> 16;  // RNE fp32 -> bf16 bits
}

// MODE 0: per-chunk per-query max -> maxes[q*CHUNKS + blk]
// MODE 1: collect scores >= thr[q] into surv[q*CAP + atomic]
template <int MODE>
__global__ __launch_bounds__(512, 2)
void score_kernel(const float* __restrict__ Q, const float* __restrict__ C,
                  float* __restrict__ maxes, const float* __restrict__ thr,
                  int* __restrict__ cnt, float* __restrict__ surv) {
  __shared__ short tile[2][NSUB * DDIM];  // 8 KB, XOR-swizzled bf16
  const int tid = threadIdx.x;
  const int lane = tid & 63;
  const int w = tid >> 6;           // wave 0..7, owns queries [w*128, w*128+128)
  const int li = lane & 15;
  const int grp = lane >> 4;
  const int wq0 = w * 128;

  // ---- Q fragments: A[m][k], m = li, k = grp*8 + j (+32 per kstep) ----
  short8 qa[8][2];
#pragma unroll
  for (int mi = 0; mi < 8; mi++) {
#pragma unroll
    for (int ks = 0; ks < 2; ks++) {
      const float* qp = Q + (wq0 + mi * 16 + li) * DDIM + ks * 32 + grp * 8;
      f32x4 a = *(const f32x4*)qp;
      f32x4 b = *(const f32x4*)(qp + 4);
      short8 f;
      f[0] = (short)f2bfu(a[0]); f[1] = (short)f2bfu(a[1]);
      f[2] = (short)f2bfu(a[2]); f[3] = (short)f2bfu(a[3]);
      f[4] = (short)f2bfu(b[0]); f[5] = (short)f2bfu(b[1]);
      f[6] = (short)f2bfu(b[2]); f[7] = (short)f2bfu(b[3]);
      qa[mi][ks] = f;
    }
  }

  f32x4 rmax[8];
  f32x4 tq[8];
  if constexpr (MODE == 0) {
#pragma unroll
    for (int mi = 0; mi < 8; mi++) rmax[mi] = (f32x4){-3.4e38f, -3.4e38f, -3.4e38f, -3.4e38f};
  } else {
#pragma unroll
    for (int mi = 0; mi < 8; mi++) tq[mi] = *(const f32x4*)(thr + wq0 + mi * 16 + grp * 4);
  }

  // ---- staging: 512 threads, thread -> (row sr, 4 floats at sk) ----
  const int sr = tid >> 4;           // 0..31
  const int sk = (tid & 15) * 4;     // 0..60
  const int swk = sk ^ ((sr & 7) << 3);  // XOR swizzle (T2): breaks 128B-row bank conflicts
  const long cbase = (long)blockIdx.x * NCHUNK;

  f32x4 sv = *(const f32x4*)(C + (cbase + sr) * DDIM + sk);
  {
    unsigned lo = f2bfu(sv[0]) | (f2bfu(sv[1]) << 16);
    unsigned hi = f2bfu(sv[2]) | (f2bfu(sv[3]) << 16);
    unsigned* p = (unsigned*)&tile[0][sr * DDIM + swk];
    p[0] = lo; p[1] = hi;
  }
  __syncthreads();

  for (int s = 0; s < NSUBS; s++) {
    if (s + 1 < NSUBS)  // issue next-subchunk global load early (latency hidden by MFMA)
      sv = *(const f32x4*)(C + (cbase + (s + 1) * NSUB + sr) * DDIM + sk);

    const short* tl = tile[s & 1];
    short8 cb[2][2];  // B[n][k] fragments, n = ni*16 + li
#pragma unroll
    for (int ni = 0; ni < 2; ni++) {
#pragma unroll
      for (int ks = 0; ks < 2; ks++) {
        int r = ni * 16 + li;
        int kb = (ks * 32 + grp * 8) ^ ((r & 7) << 3);
        cb[ni][ks] = *(const short8*)(tl + r * DDIM + kb);
      }
    }
    f32x4 acc[8][2];
    const f32x4 z = (f32x4){0.f, 0.f, 0.f, 0.f};
#pragma unroll
    for (int mi = 0; mi < 8; mi++) {
#pragma unroll
      for (int ni = 0; ni < 2; ni++) {
        f32x4 a0 = __builtin_amdgcn_mfma_f32_16x16x32_bf16(qa[mi][0], cb[ni][0], z, 0, 0, 0);
        acc[mi][ni] = __builtin_amdgcn_mfma_f32_16x16x32_bf16(qa[mi][1], cb[ni][1], a0, 0, 0, 0);
      }
    }
    // D layout: query row = grp*4 + r (+ mi*16), candidate col = li (m89-verified)
    if constexpr (MODE == 0) {
#pragma unroll
      for (int mi = 0; mi < 8; mi++) {
#pragma unroll
        for (int r = 0; r < 4; r++)
          rmax[mi][r] = fmaxf(rmax[mi][r], fmaxf(acc[mi][0][r], acc[mi][1][r]));
      }
    } else {
#pragma unroll
      for (int mi = 0; mi < 8; mi++) {
#pragma unroll
        for (int ni = 0; ni < 2; ni++) {
#pragma unroll
          for (int r = 0; r < 4; r++) {
            float sc = acc[mi][ni][r];
            if (sc >= tq[mi][r]) {
              int q = wq0 + mi * 16 + grp * 4 + r;
              int p = atomicAdd(&cnt[q], 1);
              if (p < CAP) surv[q * CAP + p] = sc;
            }
          }
        }
      }
    }

    if (s + 1 < NSUBS) {
      unsigned lo = f2bfu(sv[0]) | (f2bfu(sv[1]) << 16);
      unsigned hi = f2bfu(sv[2]) | (f2bfu(sv[3]) << 16);
      unsigned* p = (unsigned*)&tile[(s + 1) & 1][sr * DDIM + swk];
      p[0] = lo; p[1] = hi;
    }
    __syncthreads();
  }

  if constexpr (MODE == 0) {
    // reduce over the 16 candidate-lanes (li), then lanes li==0 write
#pragma unroll
    for (int mi = 0; mi < 8; mi++) {
#pragma unroll
      for (int r = 0; r < 4; r++) {
        float v = rmax[mi][r];
        v = fmaxf(v, __shfl_xor(v, 1));
        v = fmaxf(v, __shfl_xor(v, 2));
        v = fmaxf(v, __shfl_xor(v, 4));
        v = fmaxf(v, __shfl_xor(v, 8));
        rmax[mi][r] = v;
      }
    }
    if (li == 0) {
#pragma unroll
      for (int mi = 0; mi < 8; mi++) {
#pragma unroll
        for (int r = 0; r < 4; r++) {
          int q = wq0 + mi * 16 + grp * 4 + r;
          maxes[q * CHUNKS + blockIdx.x] = rmax[mi][r];
        }
      }
    }
  }
}

template <int N>
__device__ __forceinline__ void bitonic_asc(float* s) {
  for (int k = 2; k <= N; k <<= 1) {
    for (int j = k >> 1; j > 0; j >>= 1) {
      for (int i = threadIdx.x; i < N; i += blockDim.x) {
        int l = i ^ j;
        if (l > i) {
          float a = s[i], b = s[l];
          bool up = ((i & k) == 0);
          if ((a > b) == up) { s[i] = b; s[l] = a; }
        }
      }
      __syncthreads();
    }
  }
}

__global__ void thresh_kernel(const float* __restrict__ maxes, float* __restrict__ thr) {
  __shared__ float s[CHUNKS];
  int q = blockIdx.x;
  for (int i = threadIdx.x; i < CHUNKS; i += blockDim.x) s[i] = maxes[q * CHUNKS + i];
  __syncthreads();
  bitonic_asc<CHUNKS>(s);
  if (threadIdx.x == 0) thr[q] = s[CHUNKS - KTOP];  // 100th largest chunk-max
}

__global__ void final_kernel(const float* __restrict__ surv, const int* __restrict__ cnt,
                             float* __restrict__ out) {
  __shared__ float s[CAP];
  int q = blockIdx.x;
  int c = cnt[q];
  if (c > CAP) c = CAP;
  for (int i = threadIdx.x; i < CAP; i += blockDim.x)
    s[i] = (i < c) ? surv[q * CAP + i] : -3.4e38f;
  __syncthreads();
  bitonic_asc<CAP>(s);
  for (int i = threadIdx.x; i < KTOP; i += blockDim.x)
    out[q * KTOP + i] = s[CAP - 1 - i];  // descending
}

extern "C" void kernel_launch(void* const* d_in, const int* in_sizes, int n_in,
                              void* d_out, int out_size, void* d_ws, size_t ws_size,
                              hipStream_t stream) {
  const float* Q = (const float*)d_in[0];   // [1024, 64] fp32
  const float* C = (const float*)d_in[1];   // [1048576, 64] fp32
  float* out = (float*)d_out;               // [1024, 100] fp32

  char* ws = (char*)d_ws;
  float* maxes = (float*)ws;                                        // 2 MB
  float* thr   = (float*)(ws + (size_t)CHUNKS * MQTOT * 4);         // 4 KB
  int*   cnt   = (int*)(ws + (size_t)CHUNKS * MQTOT * 4 + 4096);    // 4 KB
  float* surv  = (float*)(ws + (size_t)CHUNKS * MQTOT * 4 + 8192);  // 4 MB

  hipMemsetAsync(cnt, 0, MQTOT * sizeof(int), stream);
  score_kernel<0><<<CHUNKS, 512, 0, stream>>>(Q, C, maxes, nullptr, nullptr, nullptr);
  thresh_kernel<<<MQTOT, 256, 0, stream>>>(maxes, thr);
  score_kernel<1><<<CHUNKS, 512, 0, stream>>>(Q, C, nullptr, thr, cnt, surv);
  final_kernel<<<MQTOT, 256, 0, stream>>>(surv, cnt, out);
}

// Round 2
// 413.976 us; speedup vs baseline: 1.2823x; 1.2823x over previous
//
#include <hip/hip_runtime.h>
#include <stdint.h>

#define MQTOT 1024
#define DDIM 64
#define NCAND 1048576
#define NCHUNK 2048
#define CHUNKS (NCAND / NCHUNK)   /* 512 */
#define NSUB 64
#define NSUBS (NCHUNK / NSUB)     /* 32 */
#define KTOP 100
#define CAP 1024
#define QPB 256                   /* queries per block */

typedef short short8 __attribute__((ext_vector_type(8)));
typedef float f32x4 __attribute__((ext_vector_type(4)));
typedef unsigned uix4 __attribute__((ext_vector_type(4)));

__device__ __forceinline__ unsigned f2bfu(float f) {
  unsigned u = __builtin_bit_cast(unsigned, f);
  return (u + 0x7FFFu + ((u >> 16) & 1u)) >> 16;  // RNE fp32 -> bf16 bits
}

// MODE 0: per-chunk per-query max -> maxes[q*CHUNKS + chunk]
// MODE 1: collect scores >= thr[q] into surv[q*CAP + atomic]
template <int MODE>
__global__ __launch_bounds__(256, 4)
void score_kernel(const float* __restrict__ Q, const float* __restrict__ C,
                  float* __restrict__ maxes, const float* __restrict__ thr,
                  int* __restrict__ cnt, float* __restrict__ surv) {
  __shared__ short tile[2][NSUB * DDIM];  // 2 x 8 KB bf16, granule-XOR swizzled
  const int tid = threadIdx.x;
  const int lane = tid & 63;
  const int w = tid >> 6;           // wave 0..3, owns 64 queries
  const int li = lane & 15;
  const int grp = lane >> 4;

  // XCD-aware decomposition: 4 sibling blocks (same chunk, different queries)
  // land on the same XCD, nearly consecutive -> C chunk read once from HBM,
  // 3x from that XCD's L2.  (assumes XCD = bid%8; if mapping differs this is
  // only a perf heuristic, never a correctness issue)
  const int b = blockIdx.x;
  const int xcd = b & 7;
  const int ii = b >> 3;                       // 0..255
  const int chunk = xcd * (CHUNKS / 8) + (ii >> 2);
  const int qb = ii & 3;
  const int wq0 = qb * QPB + w * 64;
  const long cbase = (long)chunk * NCHUNK;

  // ---- Q fragments: A[m][k], m = li (query row), k = grp*8 + j (+32/kstep) ----
  short8 qa[4][2];
#pragma unroll
  for (int mi = 0; mi < 4; mi++) {
#pragma unroll
    for (int ks = 0; ks < 2; ks++) {
      const float* qp = Q + (wq0 + mi * 16 + li) * DDIM + ks * 32 + grp * 8;
      f32x4 a = *(const f32x4*)qp;
      f32x4 c = *(const f32x4*)(qp + 4);
      short8 f;
      f[0] = (short)f2bfu(a[0]); f[1] = (short)f2bfu(a[1]);
      f[2] = (short)f2bfu(a[2]); f[3] = (short)f2bfu(a[3]);
      f[4] = (short)f2bfu(c[0]); f[5] = (short)f2bfu(c[1]);
      f[6] = (short)f2bfu(c[2]); f[7] = (short)f2bfu(c[3]);
      qa[mi][ks] = f;
    }
  }

  f32x4 rmax[4];
  f32x4 tq[4];
  if constexpr (MODE == 0) {
#pragma unroll
    for (int mi = 0; mi < 4; mi++) rmax[mi] = (f32x4){-3.4e38f, -3.4e38f, -3.4e38f, -3.4e38f};
  } else {
#pragma unroll
    for (int mi = 0; mi < 4; mi++) tq[mi] = *(const f32x4*)(thr + wq0 + mi * 16 + grp * 4);
  }

  // ---- staging map: 256 threads; thread -> (row sr 0..63, quarter qq 0..3) ----
  const int sr = tid >> 2;
  const int qq = tid & 3;
  const int g0 = (qq * 2) ^ (sr & 7);      // 8-short (16B) granule XOR swizzle
  const int g1 = (qq * 2 + 1) ^ (sr & 7);
  const float* srcbase = C + (cbase + sr) * DDIM + qq * 16;

  f32x4 sv[4];
#pragma unroll
  for (int j = 0; j < 4; j++) sv[j] = *(const f32x4*)(srcbase + j * 4);
  {
    uix4 p0, p1;
    p0[0] = f2bfu(sv[0][0]) | (f2bfu(sv[0][1]) << 16);
    p0[1] = f2bfu(sv[0][2]) | (f2bfu(sv[0][3]) << 16);
    p0[2] = f2bfu(sv[1][0]) | (f2bfu(sv[1][1]) << 16);
    p0[3] = f2bfu(sv[1][2]) | (f2bfu(sv[1][3]) << 16);
    p1[0] = f2bfu(sv[2][0]) | (f2bfu(sv[2][1]) << 16);
    p1[1] = f2bfu(sv[2][2]) | (f2bfu(sv[2][3]) << 16);
    p1[2] = f2bfu(sv[3][0]) | (f2bfu(sv[3][1]) << 16);
    p1[3] = f2bfu(sv[3][2]) | (f2bfu(sv[3][3]) << 16);
    *(uix4*)&tile[0][sr * DDIM + g0 * 8] = p0;
    *(uix4*)&tile[0][sr * DDIM + g1 * 8] = p1;
  }
  __syncthreads();

  for (int s = 0; s < NSUBS; s++) {
    if (s + 1 < NSUBS) {  // issue next-subchunk global loads early
      const float* nb = srcbase + (s + 1) * NSUB * DDIM;
#pragma unroll
      for (int j = 0; j < 4; j++) sv[j] = *(const f32x4*)(nb + j * 4);
    }

    const short* tl = tile[s & 1];
    short8 cb[4][2];  // B[n][k] fragments, n = ni*16 + li (candidate)
#pragma unroll
    for (int ni = 0; ni < 4; ni++) {
#pragma unroll
      for (int ks = 0; ks < 2; ks++) {
        int r = ni * 16 + li;
        int gg = (ks * 4 + grp) ^ (r & 7);
        cb[ni][ks] = *(const short8*)(tl + r * DDIM + gg * 8);
      }
    }

    const f32x4 z = (f32x4){0.f, 0.f, 0.f, 0.f};
#pragma unroll
    for (int ni = 0; ni < 4; ni++) {
      f32x4 a[4];
#pragma unroll
      for (int mi = 0; mi < 4; mi++) {
        f32x4 t0 = __builtin_amdgcn_mfma_f32_16x16x32_bf16(qa[mi][0], cb[ni][0], z, 0, 0, 0);
        a[mi] = __builtin_amdgcn_mfma_f32_16x16x32_bf16(qa[mi][1], cb[ni][1], t0, 0, 0, 0);
      }
      // D layout: query = wq0 + mi*16 + grp*4 + r, candidate = ni*16 + li
      if constexpr (MODE == 0) {
#pragma unroll
        for (int mi = 0; mi < 4; mi++) {
#pragma unroll
          for (int r = 0; r < 4; r++) rmax[mi][r] = fmaxf(rmax[mi][r], a[mi][r]);
        }
      } else {
#pragma unroll
        for (int mi = 0; mi < 4; mi++) {
#pragma unroll
          for (int r = 0; r < 4; r++) {
            float sc = a[mi][r];
            if (sc >= tq[mi][r]) {
              int q = wq0 + mi * 16 + grp * 4 + r;
              int p = atomicAdd(&cnt[q], 1);
              if (p < CAP) surv[q * CAP + p] = sc;
            }
          }
        }
      }
    }

    if (s + 1 < NSUBS) {
      uix4 p0, p1;
      p0[0] = f2bfu(sv[0][0]) | (f2bfu(sv[0][1]) << 16);
      p0[1] = f2bfu(sv[0][2]) | (f2bfu(sv[0][3]) << 16);
      p0[2] = f2bfu(sv[1][0]) | (f2bfu(sv[1][1]) << 16);
      p0[3] = f2bfu(sv[1][2]) | (f2bfu(sv[1][3]) << 16);
      p1[0] = f2bfu(sv[2][0]) | (f2bfu(sv[2][1]) << 16);
      p1[1] = f2bfu(sv[2][2]) | (f2bfu(sv[2][3]) << 16);
      p1[2] = f2bfu(sv[3][0]) | (f2bfu(sv[3][1]) << 16);
      p1[3] = f2bfu(sv[3][2]) | (f2bfu(sv[3][3]) << 16);
      short* td = tile[(s + 1) & 1];
      *(uix4*)&td[sr * DDIM + g0 * 8] = p0;
      *(uix4*)&td[sr * DDIM + g1 * 8] = p1;
    }
    __syncthreads();
  }

  if constexpr (MODE == 0) {
    // reduce over the 16 candidate-lanes (li), then li==0 writes
#pragma unroll
    for (int mi = 0; mi < 4; mi++) {
#pragma unroll
      for (int r = 0; r < 4; r++) {
        float v = rmax[mi][r];
        v = fmaxf(v, __shfl_xor(v, 1));
        v = fmaxf(v, __shfl_xor(v, 2));
        v = fmaxf(v, __shfl_xor(v, 4));
        v = fmaxf(v, __shfl_xor(v, 8));
        rmax[mi][r] = v;
      }
    }
    if (li == 0) {
#pragma unroll
      for (int mi = 0; mi < 4; mi++) {
#pragma unroll
        for (int r = 0; r < 4; r++) {
          int q = wq0 + mi * 16 + grp * 4 + r;
          maxes[q * CHUNKS + chunk] = rmax[mi][r];
        }
      }
    }
  }
}

template <int N>
__device__ __forceinline__ void bitonic_asc(float* s) {
  for (int k = 2; k <= N; k <<= 1) {
    for (int j = k >> 1; j > 0; j >>= 1) {
      for (int i = threadIdx.x; i < N; i += blockDim.x) {
        int l = i ^ j;
        if (l > i) {
          float a = s[i], b = s[l];
          bool up = ((i & k) == 0);
          if ((a > b) == up) { s[i] = b; s[l] = a; }
        }
      }
      __syncthreads();
    }
  }
}

__global__ void thresh_kernel(const float* __restrict__ maxes, float* __restrict__ thr) {
  __shared__ float s[CHUNKS];
  int q = blockIdx.x;
  for (int i = threadIdx.x; i < CHUNKS; i += blockDim.x) s[i] = maxes[q * CHUNKS + i];
  __syncthreads();
  bitonic_asc<CHUNKS>(s);
  if (threadIdx.x == 0) thr[q] = s[CHUNKS - KTOP];  // 100th-largest chunk-max
}

__global__ void final_kernel(const float* __restrict__ surv, const int* __restrict__ cnt,
                             float* __restrict__ out) {
  __shared__ float s[CAP];
  int q = blockIdx.x;
  int c = cnt[q];
  if (c > CAP) c = CAP;
  for (int i = threadIdx.x; i < CAP; i += blockDim.x)
    s[i] = (i < c) ? surv[q * CAP + i] : -3.4e38f;
  __syncthreads();
  bitonic_asc<CAP>(s);
  for (int i = threadIdx.x; i < KTOP; i += blockDim.x)
    out[q * KTOP + i] = s[CAP - 1 - i];  // descending
}

extern "C" void kernel_launch(void* const* d_in, const int* in_sizes, int n_in,
                              void* d_out, int out_size, void* d_ws, size_t ws_size,
                              hipStream_t stream) {
  const float* Q = (const float*)d_in[0];   // [1024, 64] fp32
  const float* C = (const float*)d_in[1];   // [1048576, 64] fp32
  float* out = (float*)d_out;               // [1024, 100] fp32

  char* ws = (char*)d_ws;
  float* maxes = (float*)ws;                                        // 2 MB
  float* thr   = (float*)(ws + (size_t)CHUNKS * MQTOT * 4);         // 4 KB
  int*   cnt   = (int*)(ws + (size_t)CHUNKS * MQTOT * 4 + 4096);    // 4 KB
  float* surv  = (float*)(ws + (size_t)CHUNKS * MQTOT * 4 + 8192);  // 4 MB

  hipMemsetAsync(cnt, 0, MQTOT * sizeof(int), stream);
  score_kernel<0><<<CHUNKS * 4, 256, 0, stream>>>(Q, C, maxes, nullptr, nullptr, nullptr);
  thresh_kernel<<<MQTOT, 256, 0, stream>>>(maxes, thr);
  score_kernel<1><<<CHUNKS * 4, 256, 0, stream>>>(Q, C, nullptr, thr, cnt, surv);
  final_kernel<<<MQTOT, 256, 0, stream>>>(surv, cnt, out);
}

// Round 3
// 400.087 us; speedup vs baseline: 1.3268x; 1.0347x over previous
//
#include <hip/hip_runtime.h>
#include <stdint.h>

#define MQTOT 1024
#define DDIM 64
#define NCAND 1048576
#define NCHUNK 2048
#define CHUNKS (NCAND / NCHUNK)   /* 512 */
#define NSUB 64
#define NSUBS (NCHUNK / NSUB)     /* 32 */
#define KTOP 100
#define CAP 1024
#define QPB 256
#define NSUBT (NCAND / NSUB)      /* 16384 subtiles */
#define SUBBYTES (NSUB * DDIM * 2)/* 8192 */

typedef short short8 __attribute__((ext_vector_type(8)));
typedef float f32x4 __attribute__((ext_vector_type(4)));
typedef unsigned uix4 __attribute__((ext_vector_type(4)));

__device__ __forceinline__ unsigned f2bfu(float f) {
  unsigned u = __builtin_bit_cast(unsigned, f);
  return (u + 0x7FFFu + ((u >> 16) & 1u)) >> 16;  // RNE fp32 -> bf16 bits
}

// ---------------------------------------------------------------------------
// convert: fp32 C -> bf16 C_pre, pre-swizzled per 64x64 subtile so a LINEAR
// global_load_lds copy yields the XOR-swizzled LDS image (rule 21 / m173).
// stored[r][gsw] = logical[r][gsw ^ (r&7)]  (granule = 8 bf16 = 16 B)
// ---------------------------------------------------------------------------
__global__ __launch_bounds__(512)
void convert_kernel(const float* __restrict__ C, ushort* __restrict__ CP) {
  const int sub = blockIdx.x;        // 0..16383
  const int t = threadIdx.x;         // 512 granules per subtile
  const int r = t >> 3, gsw = t & 7;
  const int g = gsw ^ (r & 7);
  const float* src = C + ((size_t)sub * NSUB + r) * DDIM + g * 8;
  f32x4 a = *(const f32x4*)src;
  f32x4 b = *(const f32x4*)(src + 4);
  uix4 p;
  p[0] = f2bfu(a[0]) | (f2bfu(a[1]) << 16);
  p[1] = f2bfu(a[2]) | (f2bfu(a[3]) << 16);
  p[2] = f2bfu(b[0]) | (f2bfu(b[1]) << 16);
  p[3] = f2bfu(b[2]) | (f2bfu(b[3]) << 16);
  *(uix4*)(CP + (size_t)sub * (NSUB * DDIM) + t * 8) = p;  // coalesced linear
}

// ---------------------------------------------------------------------------
// primary score kernel: global_load_lds(16B) -> 3-buffer LDS pipeline with
// counted vmcnt (T3/T4) + raw s_barrier. No staging VALU in the loop.
// MODE 0: per-chunk per-query max.  MODE 1: collect scores >= thr[q].
// ---------------------------------------------------------------------------
template <int MODE>
__global__ __launch_bounds__(256, 3)
void score_pre(const float* __restrict__ Q, const ushort* __restrict__ CP,
               float* __restrict__ maxes, const float* __restrict__ thr,
               int* __restrict__ cnt, float* __restrict__ surv) {
  __shared__ ushort tile[3][NSUB * DDIM];  // 3 x 8 KB
  const int tid = threadIdx.x;
  const int lane = tid & 63;
  const int li = lane & 15;
  const int grp = lane >> 4;
  const int w = tid >> 6;

  // XCD-aware: 4 sibling blocks (same chunk, different query quarters) adjacent
  const int b = blockIdx.x;
  const int xcd = b & 7;
  const int ii = b >> 3;
  const int chunk = xcd * (CHUNKS / 8) + (ii >> 2);
  const int qb = ii & 3;
  const int wq0 = qb * QPB + w * 64;

  // Q fragments: A[m][k], m = li (query), k = grp*8 + j (+32/kstep)
  short8 qa[4][2];
#pragma unroll
  for (int mi = 0; mi < 4; mi++) {
#pragma unroll
    for (int ks = 0; ks < 2; ks++) {
      const float* qp = Q + (wq0 + mi * 16 + li) * DDIM + ks * 32 + grp * 8;
      f32x4 a = *(const f32x4*)qp;
      f32x4 c = *(const f32x4*)(qp + 4);
      short8 f;
      f[0] = (short)f2bfu(a[0]); f[1] = (short)f2bfu(a[1]);
      f[2] = (short)f2bfu(a[2]); f[3] = (short)f2bfu(a[3]);
      f[4] = (short)f2bfu(c[0]); f[5] = (short)f2bfu(c[1]);
      f[6] = (short)f2bfu(c[2]); f[7] = (short)f2bfu(c[3]);
      qa[mi][ks] = f;
    }
  }

  f32x4 rmax[4];
  f32x4 tq[4];
  if constexpr (MODE == 0) {
#pragma unroll
    for (int mi = 0; mi < 4; mi++) rmax[mi] = (f32x4){-3.4e38f, -3.4e38f, -3.4e38f, -3.4e38f};
  } else {
#pragma unroll
    for (int mi = 0; mi < 4; mi++) tq[mi] = *(const f32x4*)(thr + wq0 + mi * 16 + grp * 4);
  }

  const char* cbase = (const char*)CP + (size_t)chunk * NCHUNK * DDIM * 2;
  char* lds0 = (char*)&tile[0][0];

  auto STAGE = [&](int buf, int s) {
    const char* g = cbase + (size_t)s * SUBBYTES + tid * 16;
    char* l = lds0 + buf * SUBBYTES + tid * 16;
    __builtin_amdgcn_global_load_lds((const __attribute__((address_space(1))) void*)g,
                                     (__attribute__((address_space(3))) void*)l, 16, 0, 0);
    __builtin_amdgcn_global_load_lds((const __attribute__((address_space(1))) void*)(g + 4096),
                                     (__attribute__((address_space(3))) void*)(l + 4096), 16, 0, 0);
  };

  int cur = 0;
  STAGE(0, 0);
  STAGE(1, 1);
  for (int s = 0; s < NSUBS; ++s) {
    // 2 vmcnt-increments per STAGE; keep 2 tiles in flight, never drain to 0
    if (s + 2 < NSUBS) {
      STAGE(cur >= 1 ? cur - 1 : 2, s + 2);     // (cur+2)%3
      asm volatile("s_waitcnt vmcnt(4)" ::: "memory");
    } else if (s + 1 < NSUBS) {
      asm volatile("s_waitcnt vmcnt(2)" ::: "memory");
    } else {
      asm volatile("s_waitcnt vmcnt(0)" ::: "memory");
    }
    __builtin_amdgcn_s_barrier();   // all waves' loads for tile s have landed

    const ushort* tl = &tile[0][0] + cur * (NSUB * DDIM);
    short8 cb[4][2];  // B[n][k], n = ni*16 + li (candidate row)
#pragma unroll
    for (int ni = 0; ni < 4; ni++) {
#pragma unroll
      for (int ks = 0; ks < 2; ks++) {
        int r = ni * 16 + li;
        int gg = (ks * 4 + grp) ^ (r & 7);      // undo stored swizzle
        cb[ni][ks] = *(const short8*)(tl + r * DDIM + gg * 8);
      }
    }

    f32x4 acc[4][4];  // [ni][mi]
    const f32x4 z = (f32x4){0.f, 0.f, 0.f, 0.f};
#pragma unroll
    for (int ni = 0; ni < 4; ni++) {
#pragma unroll
      for (int mi = 0; mi < 4; mi++) {
        f32x4 t0 = __builtin_amdgcn_mfma_f32_16x16x32_bf16(qa[mi][0], cb[ni][0], z, 0, 0, 0);
        acc[ni][mi] = __builtin_amdgcn_mfma_f32_16x16x32_bf16(qa[mi][1], cb[ni][1], t0, 0, 0, 0);
      }
    }

    // D layout: query = wq0 + mi*16 + grp*4 + r, candidate = ni*16 + li
    if constexpr (MODE == 0) {
#pragma unroll
      for (int mi = 0; mi < 4; mi++) {
#pragma unroll
        for (int r = 0; r < 4; r++) {
          float m01 = fmaxf(acc[0][mi][r], acc[1][mi][r]);
          float m23 = fmaxf(acc[2][mi][r], acc[3][mi][r]);
          rmax[mi][r] = fmaxf(rmax[mi][r], fmaxf(m01, m23));
        }
      }
    } else {
#pragma unroll
      for (int mi = 0; mi < 4; mi++) {
#pragma unroll
        for (int r = 0; r < 4; r++) {
          float t = tq[mi][r];
          float m01 = fmaxf(acc[0][mi][r], acc[1][mi][r]);
          float m23 = fmaxf(acc[2][mi][r], acc[3][mi][r]);
          if (fmaxf(m01, m23) >= t) {  // rare (~0.7% of waves)
            int q = wq0 + mi * 16 + grp * 4 + r;
#pragma unroll
            for (int ni = 0; ni < 4; ni++) {
              float sc = acc[ni][mi][r];
              if (sc >= t) {
                int p = atomicAdd(&cnt[q], 1);
                if (p < CAP) surv[q * CAP + p] = sc;
              }
            }
          }
        }
      }
    }

    __builtin_amdgcn_s_barrier();   // all waves done reading tile s
    cur = cur < 2 ? cur + 1 : 0;
  }

  if constexpr (MODE == 0) {
#pragma unroll
    for (int mi = 0; mi < 4; mi++) {
#pragma unroll
      for (int r = 0; r < 4; r++) {
        float v = rmax[mi][r];
        v = fmaxf(v, __shfl_xor(v, 1));
        v = fmaxf(v, __shfl_xor(v, 2));
        v = fmaxf(v, __shfl_xor(v, 4));
        v = fmaxf(v, __shfl_xor(v, 8));
        rmax[mi][r] = v;
      }
    }
    if (li == 0) {
#pragma unroll
      for (int mi = 0; mi < 4; mi++) {
#pragma unroll
        for (int r = 0; r < 4; r++) {
          int q = wq0 + mi * 16 + grp * 4 + r;
          maxes[q * CHUNKS + chunk] = rmax[mi][r];
        }
      }
    }
  }
}

// ---------------------------------------------------------------------------
// fallback (R2 kernel, reg-staged fp32 reads) — used only if ws too small
// ---------------------------------------------------------------------------
template <int MODE>
__global__ __launch_bounds__(256, 4)
void score_fb(const float* __restrict__ Q, const float* __restrict__ C,
              float* __restrict__ maxes, const float* __restrict__ thr,
              int* __restrict__ cnt, float* __restrict__ surv) {
  __shared__ short tile[2][NSUB * DDIM];
  const int tid = threadIdx.x;
  const int lane = tid & 63;
  const int w = tid >> 6;
  const int li = lane & 15;
  const int grp = lane >> 4;
  const int b = blockIdx.x;
  const int xcd = b & 7;
  const int ii = b >> 3;
  const int chunk = xcd * (CHUNKS / 8) + (ii >> 2);
  const int qb = ii & 3;
  const int wq0 = qb * QPB + w * 64;
  const long cbase = (long)chunk * NCHUNK;

  short8 qa[4][2];
#pragma unroll
  for (int mi = 0; mi < 4; mi++) {
#pragma unroll
    for (int ks = 0; ks < 2; ks++) {
      const float* qp = Q + (wq0 + mi * 16 + li) * DDIM + ks * 32 + grp * 8;
      f32x4 a = *(const f32x4*)qp;
      f32x4 c = *(const f32x4*)(qp + 4);
      short8 f;
      f[0] = (short)f2bfu(a[0]); f[1] = (short)f2bfu(a[1]);
      f[2] = (short)f2bfu(a[2]); f[3] = (short)f2bfu(a[3]);
      f[4] = (short)f2bfu(c[0]); f[5] = (short)f2bfu(c[1]);
      f[6] = (short)f2bfu(c[2]); f[7] = (short)f2bfu(c[3]);
      qa[mi][ks] = f;
    }
  }
  f32x4 rmax[4];
  f32x4 tq[4];
  if constexpr (MODE == 0) {
#pragma unroll
    for (int mi = 0; mi < 4; mi++) rmax[mi] = (f32x4){-3.4e38f, -3.4e38f, -3.4e38f, -3.4e38f};
  } else {
#pragma unroll
    for (int mi = 0; mi < 4; mi++) tq[mi] = *(const f32x4*)(thr + wq0 + mi * 16 + grp * 4);
  }
  const int sr = tid >> 2;
  const int qq = tid & 3;
  const int g0 = (qq * 2) ^ (sr & 7);
  const int g1 = (qq * 2 + 1) ^ (sr & 7);
  const float* srcbase = C + (cbase + sr) * DDIM + qq * 16;
  f32x4 sv[4];
#pragma unroll
  for (int j = 0; j < 4; j++) sv[j] = *(const f32x4*)(srcbase + j * 4);
  {
    uix4 p0, p1;
    p0[0] = f2bfu(sv[0][0]) | (f2bfu(sv[0][1]) << 16);
    p0[1] = f2bfu(sv[0][2]) | (f2bfu(sv[0][3]) << 16);
    p0[2] = f2bfu(sv[1][0]) | (f2bfu(sv[1][1]) << 16);
    p0[3] = f2bfu(sv[1][2]) | (f2bfu(sv[1][3]) << 16);
    p1[0] = f2bfu(sv[2][0]) | (f2bfu(sv[2][1]) << 16);
    p1[1] = f2bfu(sv[2][2]) | (f2bfu(sv[2][3]) << 16);
    p1[2] = f2bfu(sv[3][0]) | (f2bfu(sv[3][1]) << 16);
    p1[3] = f2bfu(sv[3][2]) | (f2bfu(sv[3][3]) << 16);
    *(uix4*)&tile[0][sr * DDIM + g0 * 8] = p0;
    *(uix4*)&tile[0][sr * DDIM + g1 * 8] = p1;
  }
  __syncthreads();
  for (int s = 0; s < NSUBS; s++) {
    if (s + 1 < NSUBS) {
      const float* nb = srcbase + (s + 1) * NSUB * DDIM;
#pragma unroll
      for (int j = 0; j < 4; j++) sv[j] = *(const f32x4*)(nb + j * 4);
    }
    const short* tl = tile[s & 1];
    short8 cb[4][2];
#pragma unroll
    for (int ni = 0; ni < 4; ni++) {
#pragma unroll
      for (int ks = 0; ks < 2; ks++) {
        int r = ni * 16 + li;
        int gg = (ks * 4 + grp) ^ (r & 7);
        cb[ni][ks] = *(const short8*)(tl + r * DDIM + gg * 8);
      }
    }
    const f32x4 z = (f32x4){0.f, 0.f, 0.f, 0.f};
#pragma unroll
    for (int ni = 0; ni < 4; ni++) {
      f32x4 a[4];
#pragma unroll
      for (int mi = 0; mi < 4; mi++) {
        f32x4 t0 = __builtin_amdgcn_mfma_f32_16x16x32_bf16(qa[mi][0], cb[ni][0], z, 0, 0, 0);
        a[mi] = __builtin_amdgcn_mfma_f32_16x16x32_bf16(qa[mi][1], cb[ni][1], t0, 0, 0, 0);
      }
      if constexpr (MODE == 0) {
#pragma unroll
        for (int mi = 0; mi < 4; mi++)
#pragma unroll
          for (int r = 0; r < 4; r++) rmax[mi][r] = fmaxf(rmax[mi][r], a[mi][r]);
      } else {
#pragma unroll
        for (int mi = 0; mi < 4; mi++)
#pragma unroll
          for (int r = 0; r < 4; r++) {
            float sc = a[mi][r];
            if (sc >= tq[mi][r]) {
              int q = wq0 + mi * 16 + grp * 4 + r;
              int p = atomicAdd(&cnt[q], 1);
              if (p < CAP) surv[q * CAP + p] = sc;
            }
          }
      }
    }
    if (s + 1 < NSUBS) {
      uix4 p0, p1;
      p0[0] = f2bfu(sv[0][0]) | (f2bfu(sv[0][1]) << 16);
      p0[1] = f2bfu(sv[0][2]) | (f2bfu(sv[0][3]) << 16);
      p0[2] = f2bfu(sv[1][0]) | (f2bfu(sv[1][1]) << 16);
      p0[3] = f2bfu(sv[1][2]) | (f2bfu(sv[1][3]) << 16);
      p1[0] = f2bfu(sv[2][0]) | (f2bfu(sv[2][1]) << 16);
      p1[1] = f2bfu(sv[2][2]) | (f2bfu(sv[2][3]) << 16);
      p1[2] = f2bfu(sv[3][0]) | (f2bfu(sv[3][1]) << 16);
      p1[3] = f2bfu(sv[3][2]) | (f2bfu(sv[3][3]) << 16);
      short* td = tile[(s + 1) & 1];
      *(uix4*)&td[sr * DDIM + g0 * 8] = p0;
      *(uix4*)&td[sr * DDIM + g1 * 8] = p1;
    }
    __syncthreads();
  }
  if constexpr (MODE == 0) {
#pragma unroll
    for (int mi = 0; mi < 4; mi++) {
#pragma unroll
      for (int r = 0; r < 4; r++) {
        float v = rmax[mi][r];
        v = fmaxf(v, __shfl_xor(v, 1));
        v = fmaxf(v, __shfl_xor(v, 2));
        v = fmaxf(v, __shfl_xor(v, 4));
        v = fmaxf(v, __shfl_xor(v, 8));
        rmax[mi][r] = v;
      }
    }
    if (li == 0) {
#pragma unroll
      for (int mi = 0; mi < 4; mi++)
#pragma unroll
        for (int r = 0; r < 4; r++) {
          int q = wq0 + mi * 16 + grp * 4 + r;
          maxes[q * CHUNKS + chunk] = rmax[mi][r];
        }
    }
  }
}

template <int N>
__device__ __forceinline__ void bitonic_asc(float* s) {
  for (int k = 2; k <= N; k <<= 1) {
    for (int j = k >> 1; j > 0; j >>= 1) {
      for (int i = threadIdx.x; i < N; i += blockDim.x) {
        int l = i ^ j;
        if (l > i) {
          float a = s[i], b = s[l];
          bool up = ((i & k) == 0);
          if ((a > b) == up) { s[i] = b; s[l] = a; }
        }
      }
      __syncthreads();
    }
  }
}

__global__ void thresh_kernel(const float* __restrict__ maxes, float* __restrict__ thr) {
  __shared__ float s[CHUNKS];
  int q = blockIdx.x;
  for (int i = threadIdx.x; i < CHUNKS; i += blockDim.x) s[i] = maxes[q * CHUNKS + i];
  __syncthreads();
  bitonic_asc<CHUNKS>(s);
  if (threadIdx.x == 0) thr[q] = s[CHUNKS - KTOP];  // 100th-largest chunk-max
}

__global__ void final_kernel(const float* __restrict__ surv, const int* __restrict__ cnt,
                             float* __restrict__ out) {
  __shared__ float s[CAP];
  int q = blockIdx.x;
  int c = cnt[q];
  if (c > CAP) c = CAP;
  for (int i = threadIdx.x; i < CAP; i += blockDim.x)
    s[i] = (i < c) ? surv[q * CAP + i] : -3.4e38f;
  __syncthreads();
  bitonic_asc<CAP>(s);
  for (int i = threadIdx.x; i < KTOP; i += blockDim.x)
    out[q * KTOP + i] = s[CAP - 1 - i];  // descending
}

extern "C" void kernel_launch(void* const* d_in, const int* in_sizes, int n_in,
                              void* d_out, int out_size, void* d_ws, size_t ws_size,
                              hipStream_t stream) {
  const float* Q = (const float*)d_in[0];   // [1024, 64] fp32
  const float* C = (const float*)d_in[1];   // [1048576, 64] fp32
  float* out = (float*)d_out;               // [1024, 100] fp32

  const size_t cpre_bytes = (size_t)NCAND * DDIM * 2;          // 128 MB
  const size_t maxes_bytes = (size_t)CHUNKS * MQTOT * 4;       // 2 MB
  const size_t need = cpre_bytes + maxes_bytes + 4096 + 4096 + (size_t)MQTOT * CAP * 4;

  char* ws = (char*)d_ws;
  if (ws_size >= need) {
    ushort* cpre = (ushort*)ws;
    float* maxes = (float*)(ws + cpre_bytes);
    float* thr   = (float*)(ws + cpre_bytes + maxes_bytes);
    int*   cnt   = (int*)(ws + cpre_bytes + maxes_bytes + 4096);
    float* surv  = (float*)(ws + cpre_bytes + maxes_bytes + 8192);

    hipMemsetAsync(cnt, 0, MQTOT * sizeof(int), stream);
    convert_kernel<<<NSUBT, 512, 0, stream>>>(C, cpre);
    score_pre<0><<<CHUNKS * 4, 256, 0, stream>>>(Q, cpre, maxes, nullptr, nullptr, nullptr);
    thresh_kernel<<<MQTOT, 256, 0, stream>>>(maxes, thr);
    score_pre<1><<<CHUNKS * 4, 256, 0, stream>>>(Q, cpre, nullptr, thr, cnt, surv);
    final_kernel<<<MQTOT, 256, 0, stream>>>(surv, cnt, out);
  } else {
    float* maxes = (float*)ws;
    float* thr   = (float*)(ws + maxes_bytes);
    int*   cnt   = (int*)(ws + maxes_bytes + 4096);
    float* surv  = (float*)(ws + maxes_bytes + 8192);

    hipMemsetAsync(cnt, 0, MQTOT * sizeof(int), stream);
    score_fb<0><<<CHUNKS * 4, 256, 0, stream>>>(Q, C, maxes, nullptr, nullptr, nullptr);
    thresh_kernel<<<MQTOT, 256, 0, stream>>>(maxes, thr);
    score_fb<1><<<CHUNKS * 4, 256, 0, stream>>>(Q, C, nullptr, thr, cnt, surv);
    final_kernel<<<MQTOT, 256, 0, stream>>>(surv, cnt, out);
  }
}